// Round 5
// baseline (3785.255 us; speedup 1.0000x reference)
//
#include <hip/hip_runtime.h>
#include <stdint.h>

typedef unsigned short u16;
typedef unsigned int   u32;
typedef __attribute__((ext_vector_type(8))) short bf16x8;
typedef __attribute__((ext_vector_type(4))) float f32x4;
typedef __attribute__((ext_vector_type(4))) u32   u32x4;

static __device__ __forceinline__ float bf2f(u16 v){
  u32 u = ((u32)v) << 16;
  return __builtin_bit_cast(float, u);
}
static __device__ __forceinline__ u16 f2bf(float f){
  u32 u = __builtin_bit_cast(u32, f);
  return (u16)((u + 0x7fffu + ((u >> 16) & 1u)) >> 16);
}

#define MFMA16(a,b,c) __builtin_amdgcn_mfma_f32_16x16x32_bf16((a),(b),(c),0,0,0)

// Model dims
#define SEQN   2048
#define PROJD  8512
#define CONVD  4352
#define INTERD 4096

// ---------------------------------------------------------------------------
// Input dtype detection (fp32 confirmed by round-2->3 NaN experiment; kept).
__global__ __launch_bounds__(256) void detect_kernel(
    const void* __restrict__ hidden, u32* __restrict__ flag)
{
  __shared__ int cnt;
  if (threadIdx.x == 0) cnt = 0;
  __syncthreads();
  if (threadIdx.x < 128){
    u16 v = ((const u16*)hidden)[threadIdx.x * 2];
    int e = (v >> 7) & 0xFF;
    int plaus = (v == 0) || (e >= 0x70 && e <= 0x8F);
    atomicAdd(&cnt, plaus);
  }
  __syncthreads();
  if (threadIdx.x == 0) *flag = (cnt < 64) ? 1u : 0u;   // 1 = fp32 inputs
}

__global__ __launch_bounds__(256) void cvt_kernel(
    const void* __restrict__ src, u16* __restrict__ dst, int n,
    const u32* __restrict__ flag)
{
  bool isf32 = (*flag != 0);
  int stride = gridDim.x * 256;
  for (int i = blockIdx.x*256 + threadIdx.x; i < n; i += stride){
    if (isf32) dst[i] = f2bf(((const float*)src)[i]);
    else       dst[i] = ((const u16*)src)[i];
  }
}

__global__ __launch_bounds__(256) void cvt_small_kernel(
    const void* cw, const void* cb, const void* al, const void* dv,
    const void* db, const void* nw, u16* __restrict__ base,
    const u32* __restrict__ flag)
{
  bool isf32 = (*flag != 0);
  int idx = blockIdx.x*256 + threadIdx.x;   // 0 .. 26047
  if (idx >= 26048) return;
  const void* src; int off;
  if      (idx < 17408){ src = cw; off = idx;          }
  else if (idx < 21760){ src = cb; off = idx - 17408;  }
  else if (idx < 21824){ src = al; off = idx - 21760;  }
  else if (idx < 21888){ src = dv; off = idx - 21824;  }
  else if (idx < 21952){ src = db; off = idx - 21888;  }
  else                 { src = nw; off = idx - 21952;  }
  u16 v = isf32 ? f2bf(((const float*)src)[off]) : ((const u16*)src)[off];
  base[idx] = v;
}

// ---------------------------------------------------------------------------
// C = A[M,K] @ B[K,N] (row-major bf16), fp32 MFMA accum.
// 128x128 tile, BK=32, 4 waves. B transposed into LDS during staging.
// mode 0: bf16 C0[row*N+col].  mode 1: proj split -> z / xbcr / dtraw (bf16).
// mode 2: fp32 CF[row*N+col]  (final output buffer is float32).
__global__ __launch_bounds__(256) void gemm_kernel(
    const u16* __restrict__ A, const u16* __restrict__ B,
    u16* __restrict__ C0, u16* __restrict__ C1, u16* __restrict__ C2,
    float* __restrict__ CF,
    int M, int N, int K, int mode)
{
  __shared__ u16 sA[128*32];
  __shared__ u16 sB[128*40];   // [n][k], stride 40 u16
  int m0 = blockIdx.y * 128, n0 = blockIdx.x * 128;
  int tid = threadIdx.x;
  int wave = tid >> 6, lane = tid & 63;
  int l15 = lane & 15, quad = lane >> 4;
  int wrow = (wave & 1) * 64, wcol = (wave >> 1) * 64;

  f32x4 acc[4][4];
  #pragma unroll
  for (int i=0;i<4;i++)
    #pragma unroll
    for (int j=0;j<4;j++) acc[i][j] = (f32x4){0.f,0.f,0.f,0.f};

  int r0 = tid >> 2, c0 = (tid & 3) * 8;

  for (int k0 = 0; k0 < K; k0 += 32){
    __syncthreads();
    u32x4 a0 = *(const u32x4*)(A + (size_t)(m0 + r0     )*K + k0 + c0);
    u32x4 a1 = *(const u32x4*)(A + (size_t)(m0 + r0 + 64)*K + k0 + c0);
    *(u32x4*)(sA + r0*32 + c0)      = a0;
    *(u32x4*)(sA + (r0+64)*32 + c0) = a1;
    #pragma unroll
    for (int it = 0; it < 2; it++){
      int ch = it*256 + tid;
      int kk2 = ch >> 4, nc = (ch & 15) * 8;
      int ncol = n0 + nc;
      if (ncol + 8 > N) ncol = N - 8;
      u32x4 v = *(const u32x4*)(B + (size_t)(k0 + kk2)*N + ncol);
      const u16* pv = (const u16*)&v;
      #pragma unroll
      for (int e = 0; e < 8; e++)
        sB[(nc + e)*40 + kk2] = pv[e];
    }
    __syncthreads();
    bf16x8 af[4], bfr[4];
    #pragma unroll
    for (int i=0;i<4;i++) af[i]  = *(const bf16x8*)(sA + (wrow + i*16 + l15)*32 + quad*8);
    #pragma unroll
    for (int j=0;j<4;j++) bfr[j] = *(const bf16x8*)(sB + (wcol + j*16 + l15)*40 + quad*8);
    #pragma unroll
    for (int i=0;i<4;i++)
      #pragma unroll
      for (int j=0;j<4;j++)
        acc[i][j] = MFMA16(af[i], bfr[j], acc[i][j]);
  }
  #pragma unroll
  for (int j=0;j<4;j++){
    int col = n0 + wcol + j*16 + l15;
    #pragma unroll
    for (int i=0;i<4;i++){
      #pragma unroll
      for (int r=0;r<4;r++){
        int row = m0 + wrow + i*16 + quad*4 + r;
        float fv = acc[i][j][r];
        if (mode == 2){
          if (col < N) CF[(size_t)row*N + col] = fv;
        } else if (mode == 0){
          if (col < N) C0[(size_t)row*N + col] = f2bf(fv);
        } else {
          u16 v = f2bf(fv);
          if      (col < 4096) C0[(size_t)row*4096 + col] = v;
          else if (col < 8448) C1[(size_t)row*CONVD + (col - 4096)] = v;
          else if (col < 8512) C2[(size_t)row*64 + (col - 8448)] = v;
        }
      }
    }
  }
}

// ---------------------------------------------------------------------------
// Causal depthwise conv (K=4, left pad 3) + bias + silu; 0.5 mup folded.
__global__ __launch_bounds__(256) void conv_silu_kernel(
    const u16* __restrict__ xbcr, const u16* __restrict__ conv_w,
    const u16* __restrict__ conv_b, u16* __restrict__ xbc)
{
  int c  = blockIdx.x * 256 + threadIdx.x;   // 17*256 = 4352 exact
  int rl = blockIdx.y;
  int b = rl >> 11, l = rl & 2047;
  float w[4];
  #pragma unroll
  for (int k=0;k<4;k++) w[k] = 0.5f * bf2f(conv_w[c*4 + k]);
  float acc = bf2f(conv_b[c]);
  #pragma unroll
  for (int k=0;k<4;k++){
    int s = l + k - 3;
    if (s >= 0) acc += bf2f(xbcr[(size_t)(b*2048 + s)*CONVD + c]) * w[k];
  }
  float sig = 1.f / (1.f + __expf(-acc));
  xbc[(size_t)rl*CONVD + c] = f2bf(acc * sig);
}

// ---------------------------------------------------------------------------
// dt_soft = softplus(dtraw + dt_bias); dA = exp(dt_soft * -exp(A_log)).
__global__ __launch_bounds__(256) void dt_kernel(
    const u16* __restrict__ dtraw, const u16* __restrict__ dt_bias,
    const u16* __restrict__ A_log, float* __restrict__ dt_soft,
    float* __restrict__ dAv)
{
  int idx = blockIdx.x * 256 + threadIdx.x;  // 4096*64
  int h = idx & 63;
  float x = bf2f(dtraw[idx]) + bf2f(dt_bias[h]);
  float sp = (x > 20.f) ? x : log1pf(expf(x));
  float A = -expf(bf2f(A_log[h]));
  dt_soft[idx] = sp;
  dAv[idx] = expf(sp * A);
}

// ---------------------------------------------------------------------------
// Exact sequential SSM scan, fp32 state in registers (exonerated in r4;
// kept this round — re-chunk after a green baseline).
__global__ __launch_bounds__(128) void ssd_seq_kernel(
    const u16* __restrict__ xbc, const float* __restrict__ dt_soft,
    const float* __restrict__ dAv, const u16* __restrict__ Dvec,
    u16* __restrict__ y)
{
  int h = blockIdx.x, b = blockIdx.y;
  int tid = threadIdx.x;
  int p = tid & 63, half = tid >> 6;
  __shared__ float sBv[128], sCv[128], sY[128];
  float st[64];
  #pragma unroll
  for (int n = 0; n < 64; n++) st[n] = 0.f;
  float Dh = bf2f(Dvec[h]);
  int nbase = half * 64;
  for (int t = 0; t < SEQN; t++){
    size_t row = (size_t)b*SEQN + t;
    const u16* xr = xbc + row*CONVD;
    sBv[tid] = bf2f(xr[4096 + tid]);
    sCv[tid] = bf2f(xr[4224 + tid]);
    float dtt = dt_soft[row*64 + h];
    float dat = dAv[row*64 + h];
    float xv  = bf2f(xr[h*64 + p]);
    __syncthreads();
    float dtx = dtt * xv;
    float ys = 0.f;
    #pragma unroll
    for (int n = 0; n < 64; n++){
      float s2 = fmaf(dat, st[n], dtx * sBv[nbase + n]);
      st[n] = s2;
      ys = fmaf(sCv[nbase + n], s2, ys);
    }
    sY[tid] = ys;
    __syncthreads();
    if (half == 0)
      y[row*INTERD + h*64 + p] = f2bf(sY[tid] + sY[tid + 64] + Dh * xv);
  }
}

// ---------------------------------------------------------------------------
// RMSNorm * norm_w, gated by silu(0.25*z) (mup z-factor folded here).
__global__ __launch_bounds__(256) void rmsnorm_gate_kernel(
    const u16* __restrict__ y, const u16* __restrict__ z,
    const u16* __restrict__ norm_w, u16* __restrict__ g)
{
  int rl = blockIdx.x;
  int tid = threadIdx.x, wave = tid >> 6, lane = tid & 63;
  const u16* yr = y + (size_t)rl*INTERD;
  float vy[16];
  float ss = 0.f;
  #pragma unroll
  for (int i = 0; i < 16; i++){
    int idx = i*256 + tid;
    float v = bf2f(yr[idx]);
    vy[i] = v;
    ss += v*v;
  }
  #pragma unroll
  for (int off = 32; off >= 1; off >>= 1) ss += __shfl_xor(ss, off, 64);
  __shared__ float red[4];
  if (lane == 0) red[wave] = ss;
  __syncthreads();
  float tot = red[0] + red[1] + red[2] + red[3];
  float rstd = rsqrtf(tot * (1.f/4096.f) + 1e-5f);
  const u16* zr = z + (size_t)rl*INTERD;
  u16* gr = g + (size_t)rl*INTERD;
  #pragma unroll
  for (int i = 0; i < 16; i++){
    int idx = i*256 + tid;
    float v = vy[i] * rstd * bf2f(norm_w[idx]);
    float zv = 0.25f * bf2f(zr[idx]);
    float sig = 1.f / (1.f + __expf(-zv));
    gr[idx] = f2bf(v * zv * sig);
  }
}

// ---------------------------------------------------------------------------
extern "C" void kernel_launch(void* const* d_in, const int* in_sizes, int n_in,
                              void* d_out, int out_size, void* d_ws, size_t ws_size,
                              hipStream_t stream)
{
  const void* hidden_r    = d_in[0];
  const void* in_proj_r   = d_in[1];
  const void* conv_w_r    = d_in[2];
  const void* conv_b_r    = d_in[3];
  const void* A_log_r     = d_in[4];
  const void* Dvec_r      = d_in[5];
  const void* dt_bias_r   = d_in[6];
  const void* norm_w_r    = d_in[7];
  const void* out_proj_r  = d_in[8];
  float* out = (float*)d_out;          // reference output dtype = float32
  char* ws = (char*)d_ws;

  // workspace layout (bytes); peak = 159,173,760
  u16*   z     = (u16*)(ws + 0);               // 33,554,432
  u16*   xbcr  = (u16*)(ws + 33554432ull);     // 35,651,584 (dead after conv)
  u16*   yb    = (u16*)(ws + 33554432ull);     // 33,554,432 overlays xbcr
  u16*   dtraw = (u16*)(ws + 69206016ull);     //    524,288
  u16*   xbc   = (u16*)(ws + 69730304ull);     // 35,651,584 (dead after ssd)
  u16*   w2b   = (u16*)(ws + 69730304ull);     // 16,777,216 overlays xbc (late)
  float* dt_s  = (float*)(ws + 105381888ull);  //  1,048,576
  float* dAv   = (float*)(ws + 106430464ull);  //  1,048,576
  u32*   flag  = (u32*)(ws + 107479040ull);    //        256
  u16*   svec  = (u16*)(ws + 107479296ull);    //     52,096 packed small vectors
  u16*   cw_b  = svec;                         // conv_w  17408
  u16*   cb_b  = svec + 17408;                 // conv_b   4352
  u16*   al_b  = svec + 21760;                 // A_log      64
  u16*   d_b   = svec + 21824;                 // D          64
  u16*   db_b  = svec + 21888;                 // dt_bias    64
  u16*   nw_b  = svec + 21952;                 // norm_w   4096
  u16*   hb    = (u16*)(ws + 107531392ull);    // 16,777,216 (dead after GEMM1)
  u16*   w1b   = (u16*)(ws + 124308608ull);    // 34,865,152 (dead after GEMM1)
  u16*   g     = (u16*)(ws + 107531392ull);    // 33,554,432 overlays hb/w1b (late)

  // 0) dtype detect + canonicalize to bf16
  detect_kernel<<<1, 256, 0, stream>>>(hidden_r, flag);
  cvt_kernel<<<4096, 256, 0, stream>>>(hidden_r,   hb,  8388608,  flag);
  cvt_kernel<<<4096, 256, 0, stream>>>(in_proj_r,  w1b, 17432576, flag);
  cvt_small_kernel<<<102, 256, 0, stream>>>(conv_w_r, conv_b_r, A_log_r,
      Dvec_r, dt_bias_r, norm_w_r, svec, flag);
  // 1) GEMM1: split epilogue -> z / xbcr / dtraw  (M=4096, N=8512, K=2048)
  gemm_kernel<<<dim3(67, 32), 256, 0, stream>>>(
      hb, w1b, z, xbcr, dtraw, (float*)nullptr, 4096, 8512, 2048, 1);
  // 2) conv + silu (0.5 mup folded)
  conv_silu_kernel<<<dim3(17, 4096), 256, 0, stream>>>(xbcr, cw_b, cb_b, xbc);
  // 3) dt softplus + per-step decay
  dt_kernel<<<1024, 256, 0, stream>>>(dtraw, db_b, al_b, dt_s, dAv);
  // 4) exact sequential SSM scan
  ssd_seq_kernel<<<dim3(64, 2), 128, 0, stream>>>(xbc, dt_s, dAv, d_b, yb);
  // 5) late conversion of out_proj into xbc's slot (xbc dead after ssd)
  cvt_kernel<<<4096, 256, 0, stream>>>(out_proj_r, w2b, 8388608, flag);
  // 6) RMSNorm + silu(0.25*z) gate (g overlays hb/w1b)
  rmsnorm_gate_kernel<<<4096, 256, 0, stream>>>(yb, z, nw_b, g);
  // 7) GEMM2: out = g @ out_proj  (M=4096, N=2048, K=4096) -> fp32 out
  gemm_kernel<<<dim3(16, 32), 256, 0, stream>>>(
      g, w2b, (u16*)nullptr, (u16*)nullptr, (u16*)nullptr, out,
      4096, 2048, 4096, 2);
}

// Round 6
// 1384.938 us; speedup vs baseline: 2.7332x; 2.7332x over previous
//
#include <hip/hip_runtime.h>
#include <stdint.h>

typedef unsigned short u16;
typedef unsigned int   u32;
typedef __attribute__((ext_vector_type(8))) short bf16x8;
typedef __attribute__((ext_vector_type(4))) float f32x4;
typedef __attribute__((ext_vector_type(4))) u32   u32x4;

static __device__ __forceinline__ float bf2f(u16 v){
  u32 u = ((u32)v) << 16;
  return __builtin_bit_cast(float, u);
}
static __device__ __forceinline__ u16 f2bf(float f){
  u32 u = __builtin_bit_cast(u32, f);
  return (u16)((u + 0x7fffu + ((u >> 16) & 1u)) >> 16);
}

#define MFMA16(a,b,c) __builtin_amdgcn_mfma_f32_16x16x32_bf16((a),(b),(c),0,0,0)

// Model dims
#define SEQN   2048
#define PROJD  8512
#define CONVD  4352
#define INTERD 4096
#define NST    128
#define QC     64
#define NCHUNK 32

// ---------------------------------------------------------------------------
// Input dtype detection (fp32 confirmed; kept for robustness).
__global__ __launch_bounds__(256) void detect_kernel(
    const void* __restrict__ hidden, u32* __restrict__ flag)
{
  __shared__ int cnt;
  if (threadIdx.x == 0) cnt = 0;
  __syncthreads();
  if (threadIdx.x < 128){
    u16 v = ((const u16*)hidden)[threadIdx.x * 2];
    int e = (v >> 7) & 0xFF;
    int plaus = (v == 0) || (e >= 0x70 && e <= 0x8F);
    atomicAdd(&cnt, plaus);
  }
  __syncthreads();
  if (threadIdx.x == 0) *flag = (cnt < 64) ? 1u : 0u;   // 1 = fp32 inputs
}

__global__ __launch_bounds__(256) void cvt_kernel(
    const void* __restrict__ src, u16* __restrict__ dst, int n,
    const u32* __restrict__ flag)
{
  bool isf32 = (*flag != 0);
  int stride = gridDim.x * 256;
  for (int i = blockIdx.x*256 + threadIdx.x; i < n; i += stride){
    if (isf32) dst[i] = f2bf(((const float*)src)[i]);
    else       dst[i] = ((const u16*)src)[i];
  }
}

__global__ __launch_bounds__(256) void cvt_small_kernel(
    const void* cw, const void* cb, const void* al, const void* dv,
    const void* db, const void* nw, u16* __restrict__ base,
    const u32* __restrict__ flag)
{
  bool isf32 = (*flag != 0);
  int idx = blockIdx.x*256 + threadIdx.x;   // 0 .. 26047
  if (idx >= 26048) return;
  const void* src; int off;
  if      (idx < 17408){ src = cw; off = idx;          }
  else if (idx < 21760){ src = cb; off = idx - 17408;  }
  else if (idx < 21824){ src = al; off = idx - 21760;  }
  else if (idx < 21888){ src = dv; off = idx - 21824;  }
  else if (idx < 21952){ src = db; off = idx - 21888;  }
  else                 { src = nw; off = idx - 21952;  }
  u16 v = isf32 ? f2bf(((const float*)src)[off]) : ((const u16*)src)[off];
  base[idx] = v;
}

// ---------------------------------------------------------------------------
// C = A[M,K] @ B[K,N] (row-major bf16), fp32 MFMA accum.
// mode 0: bf16 C0.  mode 1: proj split -> z / xbcr / dtraw.  mode 2: fp32 CF.
__global__ __launch_bounds__(256) void gemm_kernel(
    const u16* __restrict__ A, const u16* __restrict__ B,
    u16* __restrict__ C0, u16* __restrict__ C1, u16* __restrict__ C2,
    float* __restrict__ CF,
    int M, int N, int K, int mode)
{
  __shared__ u16 sA[128*32];
  __shared__ u16 sB[128*40];   // [n][k], stride 40 u16
  int m0 = blockIdx.y * 128, n0 = blockIdx.x * 128;
  int tid = threadIdx.x;
  int wave = tid >> 6, lane = tid & 63;
  int l15 = lane & 15, quad = lane >> 4;
  int wrow = (wave & 1) * 64, wcol = (wave >> 1) * 64;

  f32x4 acc[4][4];
  #pragma unroll
  for (int i=0;i<4;i++)
    #pragma unroll
    for (int j=0;j<4;j++) acc[i][j] = (f32x4){0.f,0.f,0.f,0.f};

  int r0 = tid >> 2, c0 = (tid & 3) * 8;

  for (int k0 = 0; k0 < K; k0 += 32){
    __syncthreads();
    u32x4 a0 = *(const u32x4*)(A + (size_t)(m0 + r0     )*K + k0 + c0);
    u32x4 a1 = *(const u32x4*)(A + (size_t)(m0 + r0 + 64)*K + k0 + c0);
    *(u32x4*)(sA + r0*32 + c0)      = a0;
    *(u32x4*)(sA + (r0+64)*32 + c0) = a1;
    #pragma unroll
    for (int it = 0; it < 2; it++){
      int ch = it*256 + tid;
      int kk2 = ch >> 4, nc = (ch & 15) * 8;
      int ncol = n0 + nc;
      if (ncol + 8 > N) ncol = N - 8;
      u32x4 v = *(const u32x4*)(B + (size_t)(k0 + kk2)*N + ncol);
      const u16* pv = (const u16*)&v;
      #pragma unroll
      for (int e = 0; e < 8; e++)
        sB[(nc + e)*40 + kk2] = pv[e];
    }
    __syncthreads();
    bf16x8 af[4], bfr[4];
    #pragma unroll
    for (int i=0;i<4;i++) af[i]  = *(const bf16x8*)(sA + (wrow + i*16 + l15)*32 + quad*8);
    #pragma unroll
    for (int j=0;j<4;j++) bfr[j] = *(const bf16x8*)(sB + (wcol + j*16 + l15)*40 + quad*8);
    #pragma unroll
    for (int i=0;i<4;i++)
      #pragma unroll
      for (int j=0;j<4;j++)
        acc[i][j] = MFMA16(af[i], bfr[j], acc[i][j]);
  }
  #pragma unroll
  for (int j=0;j<4;j++){
    int col = n0 + wcol + j*16 + l15;
    #pragma unroll
    for (int i=0;i<4;i++){
      #pragma unroll
      for (int r=0;r<4;r++){
        int row = m0 + wrow + i*16 + quad*4 + r;
        float fv = acc[i][j][r];
        if (mode == 2){
          if (col < N) CF[(size_t)row*N + col] = fv;
        } else if (mode == 0){
          if (col < N) C0[(size_t)row*N + col] = f2bf(fv);
        } else {
          u16 v = f2bf(fv);
          if      (col < 4096) C0[(size_t)row*4096 + col] = v;
          else if (col < 8448) C1[(size_t)row*CONVD + (col - 4096)] = v;
          else if (col < 8512) C2[(size_t)row*64 + (col - 8448)] = v;
        }
      }
    }
  }
}

// ---------------------------------------------------------------------------
// Causal depthwise conv (K=4, left pad 3) + bias + silu; 0.5 mup folded.
__global__ __launch_bounds__(256) void conv_silu_kernel(
    const u16* __restrict__ xbcr, const u16* __restrict__ conv_w,
    const u16* __restrict__ conv_b, u16* __restrict__ xbc)
{
  int c  = blockIdx.x * 256 + threadIdx.x;   // 17*256 = 4352 exact
  int rl = blockIdx.y;
  int b = rl >> 11, l = rl & 2047;
  float w[4];
  #pragma unroll
  for (int k=0;k<4;k++) w[k] = 0.5f * bf2f(conv_w[c*4 + k]);
  float acc = bf2f(conv_b[c]);
  #pragma unroll
  for (int k=0;k<4;k++){
    int s = l + k - 3;
    if (s >= 0) acc += bf2f(xbcr[(size_t)(b*2048 + s)*CONVD + c]) * w[k];
  }
  float sig = 1.f / (1.f + __expf(-acc));
  xbc[(size_t)rl*CONVD + c] = f2bf(acc * sig);
}

// ---------------------------------------------------------------------------
// dt_soft = softplus(dtraw + dt_bias); ldA = dt_soft * (-exp(A_log)).
__global__ __launch_bounds__(256) void dt_kernel(
    const u16* __restrict__ dtraw, const u16* __restrict__ dt_bias,
    const u16* __restrict__ A_log, float* __restrict__ dt_soft,
    float* __restrict__ ldA)
{
  int idx = blockIdx.x * 256 + threadIdx.x;  // 4096*64
  int h = idx & 63;
  float x = bf2f(dtraw[idx]) + bf2f(dt_bias[h]);
  float sp = (x > 20.f) ? x : log1pf(expf(x));
  float A = -expf(bf2f(A_log[h]));
  dt_soft[idx] = sp;
  ldA[idx] = sp * A;
}

__global__ __launch_bounds__(256) void chunk_decay_kernel(
    const float* __restrict__ ldA, float* __restrict__ cdexp)
{
  int idx = blockIdx.x * 256 + threadIdx.x;  // 4096
  int q = idx & 31, bh = idx >> 5;
  int b = bh >> 6, h = bh & 63;
  float s = 0.f;
  int t0 = q * QC;
  for (int t = 0; t < QC; t++) s += ldA[(size_t)(b*2048 + t0 + t)*64 + h];
  cdexp[idx] = expf(s);
}

// ---------------------------------------------------------------------------
// SSD intra-chunk (validated in r4 bisection: matches exact scan).
#define SBS  136
#define SUTS 80
#define SMS  80
__global__ __launch_bounds__(256) void ssd_intra_kernel(
    const u16* __restrict__ xbc, const float* __restrict__ dt_soft,
    const float* __restrict__ ldA, u16* __restrict__ S,
    u16* __restrict__ y)
{
  int q = blockIdx.x, h = blockIdx.y, b = blockIdx.z;
  int bh = b*64 + h;
  int t0 = q * QC;
  int tid = threadIdx.x, wave = tid >> 6, lane = tid & 63;
  int l15 = lane & 15, quad = lane >> 4;

  __shared__ u16 sB [64*SBS];
  __shared__ u16 sCM[64*SBS];
  __shared__ u16 sBt[128*64];
  __shared__ u16 sUt[64*SUTS];
  __shared__ float sLa[64];
  __shared__ float sW[64];

  if (tid < 64){
    float v = ldA[(size_t)(b*2048 + t0 + tid)*64 + h];
    #pragma unroll
    for (int off = 1; off < 64; off <<= 1){
      float o = __shfl_up(v, off, 64);
      if (lane >= off) v += o;
    }
    sLa[tid] = v;
  }
  __syncthreads();
  float laE = sLa[63];
  if (tid < 64) sW[tid] = __expf(laE - sLa[tid]);
  __syncthreads();

  #pragma unroll
  for (int i = 0; i < 4; i++){
    int ch = i*256 + tid;
    int s = ch >> 4, nc = (ch & 15) * 8;
    const u16* src = xbc + (size_t)(b*2048 + t0 + s)*CONVD;
    u32x4 vb = *(const u32x4*)(src + 4096 + nc);
    u32x4 vc = *(const u32x4*)(src + 4224 + nc);
    *(u32x4*)(sB  + s*SBS + nc) = vb;
    *(u32x4*)(sCM + s*SBS + nc) = vc;
    float wdec = sW[s];
    const u16* pb = (const u16*)&vb;
    #pragma unroll
    for (int e = 0; e < 8; e++)
      sBt[(nc + e)*64 + s] = f2bf(bf2f(pb[e]) * wdec);
  }
  #pragma unroll
  for (int i = 0; i < 2; i++){
    int ch = i*256 + tid;
    int s = ch >> 3, pc = (ch & 7) * 8;
    const u16* src = xbc + (size_t)(b*2048 + t0 + s)*CONVD + h*64 + pc;
    u32x4 vx = *(const u32x4*)src;
    float dt = dt_soft[(size_t)(b*2048 + t0 + s)*64 + h];
    const u16* px = (const u16*)&vx;
    #pragma unroll
    for (int e = 0; e < 8; e++)
      sUt[(pc + e)*SUTS + s] = f2bf(bf2f(px[e]) * dt);
  }
  __syncthreads();

  // MFMA1: M[t][s] = sum_n C[t][n]*B[s][n]
  int tr = (wave & 1)*32, sc = (wave >> 1)*32;
  f32x4 aM[2][2];
  #pragma unroll
  for (int i=0;i<2;i++)
    #pragma unroll
    for (int j=0;j<2;j++) aM[i][j] = (f32x4){0.f,0.f,0.f,0.f};
  #pragma unroll
  for (int kk = 0; kk < 128; kk += 32){
    bf16x8 a0 = *(const bf16x8*)(sCM + (tr      + l15)*SBS + kk + quad*8);
    bf16x8 a1 = *(const bf16x8*)(sCM + (tr + 16 + l15)*SBS + kk + quad*8);
    bf16x8 b0 = *(const bf16x8*)(sB  + (sc      + l15)*SBS + kk + quad*8);
    bf16x8 b1 = *(const bf16x8*)(sB  + (sc + 16 + l15)*SBS + kk + quad*8);
    aM[0][0] = MFMA16(a0, b0, aM[0][0]);
    aM[0][1] = MFMA16(a0, b1, aM[0][1]);
    aM[1][0] = MFMA16(a1, b0, aM[1][0]);
    aM[1][1] = MFMA16(a1, b1, aM[1][1]);
  }
  __syncthreads();
  u16* sM = sCM;
  #pragma unroll
  for (int i = 0; i < 2; i++){
    #pragma unroll
    for (int j = 0; j < 2; j++){
      int scol = sc + j*16 + l15;
      #pragma unroll
      for (int r = 0; r < 4; r++){
        int trow = tr + i*16 + quad*4 + r;
        float v = 0.f;
        if (scol <= trow) v = aM[i][j][r] * __expf(sLa[trow] - sLa[scol]);
        sM[trow*SMS + scol] = f2bf(v);
      }
    }
  }
  __syncthreads();

  // MFMA2: Y[t][p] = sum_s M[t][s]*u[s][p]
  f32x4 aY[2][2];
  #pragma unroll
  for (int i=0;i<2;i++)
    #pragma unroll
    for (int j=0;j<2;j++) aY[i][j] = (f32x4){0.f,0.f,0.f,0.f};
  #pragma unroll
  for (int kk = 0; kk < 64; kk += 32){
    bf16x8 a0 = *(const bf16x8*)(sM  + (tr      + l15)*SMS  + kk + quad*8);
    bf16x8 a1 = *(const bf16x8*)(sM  + (tr + 16 + l15)*SMS  + kk + quad*8);
    bf16x8 b0 = *(const bf16x8*)(sUt + (sc      + l15)*SUTS + kk + quad*8);
    bf16x8 b1 = *(const bf16x8*)(sUt + (sc + 16 + l15)*SUTS + kk + quad*8);
    aY[0][0] = MFMA16(a0, b0, aY[0][0]);
    aY[0][1] = MFMA16(a0, b1, aY[0][1]);
    aY[1][0] = MFMA16(a1, b0, aY[1][0]);
    aY[1][1] = MFMA16(a1, b1, aY[1][1]);
  }
  #pragma unroll
  for (int i = 0; i < 2; i++){
    #pragma unroll
    for (int j = 0; j < 2; j++){
      int p = sc + j*16 + l15;
      #pragma unroll
      for (int r = 0; r < 4; r++){
        int t = tr + i*16 + quad*4 + r;
        y[(size_t)(b*2048 + t0 + t)*INTERD + h*64 + p] = f2bf(aY[i][j][r]);
      }
    }
  }

  // MFMA3: S[p][n] = sum_s u[s][p]*decay(s)*B[s][n]
  int pr = (wave & 1)*32, nw = (wave >> 1)*64;
  f32x4 aS[2][4];
  #pragma unroll
  for (int i=0;i<2;i++)
    #pragma unroll
    for (int j=0;j<4;j++) aS[i][j] = (f32x4){0.f,0.f,0.f,0.f};
  #pragma unroll
  for (int kk = 0; kk < 64; kk += 32){
    bf16x8 a0 = *(const bf16x8*)(sUt + (pr      + l15)*SUTS + kk + quad*8);
    bf16x8 a1 = *(const bf16x8*)(sUt + (pr + 16 + l15)*SUTS + kk + quad*8);
    #pragma unroll
    for (int j = 0; j < 4; j++){
      bf16x8 bb = *(const bf16x8*)(sBt + (nw + j*16 + l15)*64 + kk + quad*8);
      aS[0][j] = MFMA16(a0, bb, aS[0][j]);
      aS[1][j] = MFMA16(a1, bb, aS[1][j]);
    }
  }
  u16* Sl = S + ((size_t)bh*NCHUNK + q)*8192;
  #pragma unroll
  for (int i = 0; i < 2; i++){
    #pragma unroll
    for (int j = 0; j < 4; j++){
      int n = nw + j*16 + l15;
      #pragma unroll
      for (int r = 0; r < 4; r++){
        int p = pr + i*16 + quad*4 + r;
        Sl[p*NST + n] = f2bf(aS[i][j][r]);
      }
    }
  }
}

// ---------------------------------------------------------------------------
// Inter-chunk recurrence, in-place.
__global__ __launch_bounds__(256) void ssd_carry_kernel(
    u16* __restrict__ S, const float* __restrict__ cdexp)
{
  int idx = blockIdx.x * 256 + threadIdx.x;   // 2*64*8192
  int e = idx & 8191, bh = idx >> 13;
  float E = 0.f;
  for (int q = 0; q < NCHUNK; q++){
    size_t off = ((size_t)bh*NCHUNK + q)*8192 + e;
    float v = bf2f(S[off]);
    S[off] = f2bf(E);
    E = cdexp[bh*NCHUNK + q] * E + v;
  }
}

// ---------------------------------------------------------------------------
// Inter-chunk output: y += exp(la[t]) * C_t @ S_q^T + D*x
__global__ __launch_bounds__(256) void ssd_inter_kernel(
    const u16* __restrict__ xbc, const float* __restrict__ ldA,
    const u16* __restrict__ S, const u16* __restrict__ Dvec,
    u16* __restrict__ y)
{
  int q = blockIdx.x, h = blockIdx.y, b = blockIdx.z;
  int bh = b*64 + h;
  int t0 = q * QC;
  int tid = threadIdx.x, wave = tid >> 6, lane = tid & 63;
  int l15 = lane & 15, quad = lane >> 4;

  __shared__ u16 sC[64*SBS];
  __shared__ u16 sS[64*SBS];
  __shared__ float sLa[64];

  if (tid < 64){
    float v = ldA[(size_t)(b*2048 + t0 + tid)*64 + h];
    #pragma unroll
    for (int off = 1; off < 64; off <<= 1){
      float o = __shfl_up(v, off, 64);
      if (lane >= off) v += o;
    }
    sLa[tid] = v;
  }
  const u16* Sc = S + ((size_t)bh*NCHUNK + q)*8192;
  #pragma unroll
  for (int i = 0; i < 4; i++){
    int ch = i*256 + tid;
    int s = ch >> 4, nc = (ch & 15) * 8;
    *(u32x4*)(sC + s*SBS + nc) =
        *(const u32x4*)(xbc + (size_t)(b*2048 + t0 + s)*CONVD + 4224 + nc);
    *(u32x4*)(sS + s*SBS + nc) = *(const u32x4*)(Sc + s*NST + nc);
  }
  __syncthreads();

  int tr = (wave & 1)*32, pc = (wave >> 1)*32;
  f32x4 acc[2][2];
  #pragma unroll
  for (int i=0;i<2;i++)
    #pragma unroll
    for (int j=0;j<2;j++) acc[i][j] = (f32x4){0.f,0.f,0.f,0.f};
  #pragma unroll
  for (int kk = 0; kk < 128; kk += 32){
    bf16x8 a0 = *(const bf16x8*)(sC + (tr      + l15)*SBS + kk + quad*8);
    bf16x8 a1 = *(const bf16x8*)(sC + (tr + 16 + l15)*SBS + kk + quad*8);
    bf16x8 b0 = *(const bf16x8*)(sS + (pc      + l15)*SBS + kk + quad*8);
    bf16x8 b1 = *(const bf16x8*)(sS + (pc + 16 + l15)*SBS + kk + quad*8);
    acc[0][0] = MFMA16(a0, b0, acc[0][0]);
    acc[0][1] = MFMA16(a0, b1, acc[0][1]);
    acc[1][0] = MFMA16(a1, b0, acc[1][0]);
    acc[1][1] = MFMA16(a1, b1, acc[1][1]);
  }
  float Dh = bf2f(Dvec[h]);
  #pragma unroll
  for (int i = 0; i < 2; i++){
    #pragma unroll
    for (int j = 0; j < 2; j++){
      int p = pc + j*16 + l15;
      #pragma unroll
      for (int r = 0; r < 4; r++){
        int t = tr + i*16 + quad*4 + r;
        size_t row = (size_t)(b*2048 + t0 + t);
        size_t yo = row*INTERD + h*64 + p;
        float xv = bf2f(xbc[row*CONVD + h*64 + p]);
        float v = bf2f(y[yo]) + __expf(sLa[t]) * acc[i][j][r] + Dh * xv;
        y[yo] = f2bf(v);
      }
    }
  }
}

// ---------------------------------------------------------------------------
// RMSNorm * norm_w, gated by silu(0.25*z).
__global__ __launch_bounds__(256) void rmsnorm_gate_kernel(
    const u16* __restrict__ y, const u16* __restrict__ z,
    const u16* __restrict__ norm_w, u16* __restrict__ g)
{
  int rl = blockIdx.x;
  int tid = threadIdx.x, wave = tid >> 6, lane = tid & 63;
  const u16* yr = y + (size_t)rl*INTERD;
  float vy[16];
  float ss = 0.f;
  #pragma unroll
  for (int i = 0; i < 16; i++){
    int idx = i*256 + tid;
    float v = bf2f(yr[idx]);
    vy[i] = v;
    ss += v*v;
  }
  #pragma unroll
  for (int off = 32; off >= 1; off >>= 1) ss += __shfl_xor(ss, off, 64);
  __shared__ float red[4];
  if (lane == 0) red[wave] = ss;
  __syncthreads();
  float tot = red[0] + red[1] + red[2] + red[3];
  float rstd = rsqrtf(tot * (1.f/4096.f) + 1e-5f);
  const u16* zr = z + (size_t)rl*INTERD;
  u16* gr = g + (size_t)rl*INTERD;
  #pragma unroll
  for (int i = 0; i < 16; i++){
    int idx = i*256 + tid;
    float v = vy[i] * rstd * bf2f(norm_w[idx]);
    float zv = 0.25f * bf2f(zr[idx]);
    float sig = 1.f / (1.f + __expf(-zv));
    gr[idx] = f2bf(v * zv * sig);
  }
}

// ---------------------------------------------------------------------------
extern "C" void kernel_launch(void* const* d_in, const int* in_sizes, int n_in,
                              void* d_out, int out_size, void* d_ws, size_t ws_size,
                              hipStream_t stream)
{
  const void* hidden_r    = d_in[0];
  const void* in_proj_r   = d_in[1];
  const void* conv_w_r    = d_in[2];
  const void* conv_b_r    = d_in[3];
  const void* A_log_r     = d_in[4];
  const void* Dvec_r      = d_in[5];
  const void* dt_bias_r   = d_in[6];
  const void* norm_w_r    = d_in[7];
  const void* out_proj_r  = d_in[8];
  float* out = (float*)d_out;          // reference output dtype = float32
  char* ws = (char*)d_ws;

  // workspace layout (bytes); peak = 174,735,360 (proven in-bounds in r3)
  u16*   z     = (u16*)(ws + 0);               // 33,554,432
  u16*   xbcr  = (u16*)(ws + 33554432ull);     // 35,651,584 (dead after conv)
  u16*   yb    = (u16*)(ws + 33554432ull);     // 33,554,432 overlays xbcr
  u16*   dtraw = (u16*)(ws + 69206016ull);     //    524,288
  u16*   xbc   = (u16*)(ws + 69730304ull);     // 35,651,584 (dead after inter)
  u16*   w2b   = (u16*)(ws + 69730304ull);     // 16,777,216 overlays xbc (late)
  float* dt_s  = (float*)(ws + 105381888ull);  //  1,048,576
  float* lda   = (float*)(ws + 106430464ull);  //  1,048,576
  float* cdexp = (float*)(ws + 107479040ull);  //     16,384
  u32*   flag  = (u32*)(ws + 107495424ull);    //        256
  u16*   svec  = (u16*)(ws + 107495680ull);    //     52,096 packed small vectors
  u16*   cw_b  = svec;                         // conv_w  17408
  u16*   cb_b  = svec + 17408;                 // conv_b   4352
  u16*   al_b  = svec + 21760;                 // A_log      64
  u16*   d_b   = svec + 21824;                 // D          64
  u16*   db_b  = svec + 21888;                 // dt_bias    64
  u16*   nw_b  = svec + 21952;                 // norm_w   4096
  u16*   S     = (u16*)(ws + 107626496ull);    // 67,108,864 -> end 174,735,360
  u16*   hb    = (u16*)(ws + 107626496ull);    // 16,777,216 overlays S (early)
  u16*   w1b   = (u16*)(ws + 124403712ull);    // 34,865,152 overlays S (early)
  u16*   g     = (u16*)(ws + 107626496ull);    // 33,554,432 overlays S (late)

  // 0) dtype detect + canonicalize to bf16
  detect_kernel<<<1, 256, 0, stream>>>(hidden_r, flag);
  cvt_kernel<<<4096, 256, 0, stream>>>(hidden_r,   hb,  8388608,  flag);
  cvt_kernel<<<4096, 256, 0, stream>>>(in_proj_r,  w1b, 17432576, flag);
  cvt_small_kernel<<<102, 256, 0, stream>>>(conv_w_r, conv_b_r, A_log_r,
      Dvec_r, dt_bias_r, norm_w_r, svec, flag);
  // 1) GEMM1: split epilogue -> z / xbcr / dtraw  (M=4096, N=8512, K=2048)
  gemm_kernel<<<dim3(67, 32), 256, 0, stream>>>(
      hb, w1b, z, xbcr, dtraw, (float*)nullptr, 4096, 8512, 2048, 1);
  // 2) conv + silu (0.5 mup folded)
  conv_silu_kernel<<<dim3(17, 4096), 256, 0, stream>>>(xbcr, cw_b, cb_b, xbc);
  // 3) dt softplus + log-decays
  dt_kernel<<<1024, 256, 0, stream>>>(dtraw, db_b, al_b, dt_s, lda);
  chunk_decay_kernel<<<16, 256, 0, stream>>>(lda, cdexp);
  // 4) SSD chunked scan (validated against exact scan in r4)
  ssd_intra_kernel<<<dim3(NCHUNK, 64, 2), 256, 0, stream>>>(xbc, dt_s, lda, S, yb);
  ssd_carry_kernel<<<4096, 256, 0, stream>>>(S, cdexp);
  ssd_inter_kernel<<<dim3(NCHUNK, 64, 2), 256, 0, stream>>>(xbc, lda, S, d_b, yb);
  // 5) late conversion of out_proj into xbc's slot (xbc dead after inter)
  cvt_kernel<<<4096, 256, 0, stream>>>(out_proj_r, w2b, 8388608, flag);
  // 6) RMSNorm + silu(0.25*z) gate (g overlays S)
  rmsnorm_gate_kernel<<<4096, 256, 0, stream>>>(yb, z, nw_b, g);
  // 7) GEMM2: out = g @ out_proj  (M=4096, N=2048, K=4096) -> fp32 out
  gemm_kernel<<<dim3(16, 32), 256, 0, stream>>>(
      g, w2b, (u16*)nullptr, (u16*)nullptr, (u16*)nullptr, out,
      4096, 2048, 4096, 2);
}